// Round 8
// baseline (64.198 us; speedup 1.0000x reference)
//
#include <hip/hip_runtime.h>
#include <math.h>
#include <stdint.h>

#define EPS 1e-12f
#define REPS 4    // INSTRUMENTATION: inner-repeat MFMA loop; only last rep kept
#define EPREPS 4  // INSTRUMENTATION: repeat epilogue (idempotent re-stores)

typedef __attribute__((ext_vector_type(8))) short short8v;   // 8 bf16, 4 VGPRs
typedef __attribute__((ext_vector_type(8))) unsigned short us8;
typedef __attribute__((ext_vector_type(4))) float f32x4;

__device__ __forceinline__ unsigned short f2bf(float f) {
  union { float f; uint32_t u; } c; c.f = f;
  uint32_t u = c.u;
  uint32_t r = (u + 0x7FFFu + ((u >> 16) & 1u)) >> 16;  // RNE
  return (unsigned short)r;
}

__device__ __forceinline__ void gl_lds16(const void* g, void* l) {
  __builtin_amdgcn_global_load_lds(
      (const __attribute__((address_space(1))) unsigned int*)g,
      (__attribute__((address_space(3))) unsigned int*)l, 16, 0, 0);
}

// ---------------------------------------------------------------------------
// Workspace: Wb [9][128][64] bf16 @ 0 (147456 B), c-chunks XOR-swizzled by v&7
// ---------------------------------------------------------------------------

__global__ __launch_bounds__(256) void prep_wb(
    const float* __restrict__ w, const float* __restrict__ q,
    unsigned short* __restrict__ Wb) {
  int tid = threadIdx.x;
  int v = blockIdx.x * 4 + (tid >> 6);
  int c = tid & 63;
  float qn = q[0] * 0.01f;
  float scale = qn * qn;
  const float* wp = w + (v * 64 + c) * 9;
  float vals[9];
  float ss = 0.f;
#pragma unroll
  for (int j = 0; j < 9; ++j) { vals[j] = wp[j]; ss += vals[j] * vals[j]; }
#pragma unroll
  for (int off = 32; off > 0; off >>= 1) ss += __shfl_xor(ss, off);
  float inv = 1.0f / (sqrtf(ss + EPS) + scale);
  int pos = (((c >> 3) ^ (v & 7)) << 3) | (c & 7);
#pragma unroll
  for (int j = 0; j < 9; ++j) Wb[(j * 128 + v) * 64 + pos] = f2bf(vals[j] * inv);
}

// Fused conv, DOUBLE-INSTRUMENTED: MFMA loop x REPS, epilogue x EPREPS.
// Early loop reps kept live via sink; epilogue reps are idempotent re-stores
// with opaque-zero preventing CSE/DSE. Plain (non-NT) stores this round.
__global__ __launch_bounds__(256, 2) void conv_fused(
    const float* __restrict__ x, const unsigned short* __restrict__ Wb,
    const float* __restrict__ p, const float* __restrict__ q,
    float* __restrict__ out) {
  __shared__ unsigned short xs[4 * 66 * 64];  // [row][w+1][c] 33792 B, padded w
  __shared__ unsigned short wl[2 * 128 * 64]; // dbuf weight tiles, 32768 B
  __shared__ float sf[4 * 64];                // channel sq-sums of staged rows
  __shared__ float xiv[2 * 64];               // 1/(sqrt(box3x3)+scale)

  int b = blockIdx.x;              // 512 = 16 n x 32 row-pairs
  int n = b >> 5, hg = b & 31;
  int h0 = hg * 2;
  int tid = threadIdx.x;
  int lane = tid & 63, wid = tid >> 6;
  int wv = wid & 1, wp = wid >> 1;     // v-half, output row
  int lp = lane & 15, lg = lane >> 4;

  auto stage_w = [&](int bufi, int l) {
    const unsigned short* src = Wb + l * 8192 + wid * 2048;
    unsigned short* dst = wl + bufi * 8192 + wid * 2048;
#pragma unroll
    for (int i = 0; i < 4; ++i)
      gl_lds16(src + i * 512 + lane * 8, dst + i * 512);
  };
  stage_w(0, 0);

  // ---- stage x rows h0-1 .. h0+2 (one row per wave), fp32->bf16 + sq-sum ----
  {
    int hh = h0 - 1 + wid;
    int w = lane;
    unsigned short* xrow = xs + wid * 4224 + (w + 1) * 64;
    if ((unsigned)hh < 64u) {
      const float* xp = x + ((size_t)n << 18) + hh * 64 + w;
      float ss = 0.f;
#pragma unroll
      for (int j = 0; j < 8; ++j) {
        float v[8];
#pragma unroll
        for (int e = 0; e < 8; ++e) v[e] = xp[(j * 8 + e) * 4096];
        us8 pk;
#pragma unroll
        for (int e = 0; e < 8; ++e) { ss += v[e] * v[e]; pk[e] = f2bf(v[e]); }
        *(us8*)(xrow + ((j ^ (w & 7)) * 8)) = pk;
      }
      sf[wid * 64 + w] = ss;
    } else {
      us8 z = {};
#pragma unroll
      for (int j = 0; j < 8; ++j) *(us8*)(xrow + j * 8) = z;
      sf[wid * 64 + w] = 0.f;
    }
  }
  if (tid < 64) {
    int row = tid >> 4, side = (tid >> 3) & 1, j = tid & 7;
    us8 z = {};
    *(us8*)(xs + row * 4224 + (side ? 65 : 0) * 64 + j * 8) = z;
  }
  __syncthreads();   // xs, sf, wl(l=0) ready (vmcnt drained)

  if (tid < 128) {
    int r = tid >> 6, w = tid & 63;
    float qn = q[0] * 0.01f;
    float scale = qn * qn;
    float a = 0.f;
#pragma unroll
    for (int dr = 0; dr < 3; ++dr) {
      const float* base = sf + (r + dr) * 64;
      a += base[w];
      if (w > 0) a += base[w - 1];
      if (w < 63) a += base[w + 1];
    }
    xiv[r * 64 + w] = 1.0f / (sqrtf(a + EPS) + scale);
  }

  f32x4 acc[4][4];   // [pg][vg]
  float sink = 0.f;

#pragma unroll 1
  for (int rep = 0; rep < REPS; ++rep) {
    if (rep > 0) {           // restore wl[0] = tile 0 for this rep
      stage_w(0, 0);
      __syncthreads();
    }
#pragma unroll
    for (int i = 0; i < 4; ++i)
#pragma unroll
      for (int j = 0; j < 4; ++j) acc[i][j] = (f32x4){0.f, 0.f, 0.f, 0.f};

    int buf = 0;
#pragma unroll
    for (int l = 0; l < 9; ++l) {
      if (l < 8) stage_w(buf ^ 1, l + 1);
      const int a = l / 3, bs = l % 3;
      const unsigned short* xrow = xs + (wp + a) * 4224;
      const unsigned short* wbase = wl + buf * 8192 + wv * 4096;
#pragma unroll
      for (int half = 0; half < 2; ++half) {
        const int cbase = half * 4;
        short8v av[4], bv[4];
#pragma unroll
        for (int vg = 0; vg < 4; ++vg)
          av[vg] = *(const short8v*)(wbase + (vg * 16 + lp) * 64 +
                                     ((cbase + lg) ^ (lp & 7)) * 8);
#pragma unroll
        for (int pg = 0; pg < 4; ++pg) {
          int wx = pg * 16 + lp + bs - 1;
          bv[pg] = *(const short8v*)(xrow + (wx + 1) * 64 +
                                     ((cbase + lg) ^ (wx & 7)) * 8);
        }
#pragma unroll
        for (int pg = 0; pg < 4; ++pg)
#pragma unroll
          for (int vg = 0; vg < 4; ++vg)
            acc[pg][vg] = __builtin_amdgcn_mfma_f32_16x16x32_bf16(
                bv[pg], av[vg], acc[pg][vg], 0, 0, 0);
      }
      if (l < 8) {
        __syncthreads();
        buf ^= 1;
      }
    }
    if (rep != REPS - 1) {   // keep this rep's MFMAs live (anti-DCE, rule #17)
#pragma unroll
      for (int i = 0; i < 4; ++i)
#pragma unroll
        for (int j = 0; j < 4; ++j)
#pragma unroll
          for (int r = 0; r < 4; ++r) sink += acc[i][j][r];
      __syncthreads();       // all waves done with wl before re-stage
    }
  }
  if (sink == 12345.678125f && lane == 63 && tid == 0) out[0] = sink;

  // ---- epilogue x EPREPS: opaque-zero defeats CSE (math) and DSE (stores) ----
  int h = h0 + wp;
  float opzf;
  int opzi;
  asm volatile("v_mov_b32 %0, 0" : "=v"(opzf));
  asm volatile("v_mov_b32 %0, 0" : "=v"(opzi));
#pragma unroll 1
  for (int er = 0; er < EPREPS; ++er) {
    float ez = opzf * (float)er;          // runtime 0, opaque to compiler
    size_t az = (size_t)(opzi * er);      // runtime 0, opaque to compiler
#pragma unroll
    for (int vg = 0; vg < 4; ++vg) {
      int v = wv * 64 + vg * 16 + lp;
      float t0 = p[v] * 0.1f;
      float e = t0 * t0;
      float* ob = out + ((size_t)(n * 128 + v)) * 4096 + h * 64 + az;
#pragma unroll
      for (int pg = 0; pg < 4; ++pg) {
        int w4 = pg * 16 + lg * 4;
        float4 xv = *(const float4*)&xiv[wp * 64 + w4];
        float yv[4] = {acc[pg][vg][0] * xv.x + ez, acc[pg][vg][1] * xv.y + ez,
                       acc[pg][vg][2] * xv.z + ez, acc[pg][vg][3] * xv.w + ez};
        f32x4 o;
#pragma unroll
        for (int r = 0; r < 4; ++r) {
          float y = yv[r];
          float t = fabsf(y) + EPS;
          float rv = exp2f(e * log2f(t));
          o[r] = (y == 0.0f) ? 0.0f : copysignf(rv, y);
        }
        *(f32x4*)(ob + w4) = o;           // plain store (NT dropped)
      }
    }
  }
}

extern "C" void kernel_launch(void* const* d_in, const int* in_sizes, int n_in,
                              void* d_out, int out_size, void* d_ws, size_t ws_size,
                              hipStream_t stream) {
  const float* x = (const float*)d_in[0];   // [16,64,64,64]
  const float* w = (const float*)d_in[1];   // [128,64,9]
  const float* p = (const float*)d_in[2];   // [128]
  const float* q = (const float*)d_in[3];   // [1]
  float* out = (float*)d_out;               // [16,128,64,64]

  unsigned short* Wb = (unsigned short*)d_ws;

  prep_wb<<<32, 256, 0, stream>>>(w, q, Wb);
  conv_fused<<<512, 256, 0, stream>>>(x, Wb, p, q, out);
}

// Round 9
// 33.733 us; speedup vs baseline: 1.9031x; 1.9031x over previous
//
#include <hip/hip_runtime.h>
#include <math.h>
#include <stdint.h>

#define EPS 1e-12f

typedef __attribute__((ext_vector_type(8))) short short8v;   // 8 bf16, 4 VGPRs
typedef __attribute__((ext_vector_type(8))) unsigned short us8;
typedef __attribute__((ext_vector_type(4))) float f32x4;

__device__ __forceinline__ unsigned short f2bf(float f) {
  union { float f; uint32_t u; } c; c.f = f;
  uint32_t u = c.u;
  uint32_t r = (u + 0x7FFFu + ((u >> 16) & 1u)) >> 16;  // RNE
  return (unsigned short)r;
}

__device__ __forceinline__ void gl_lds16(const void* g, void* l) {
  __builtin_amdgcn_global_load_lds(
      (const __attribute__((address_space(1))) unsigned int*)g,
      (__attribute__((address_space(3))) unsigned int*)l, 16, 0, 0);
}

// ---------------------------------------------------------------------------
// Workspace layout (bytes):
//   xT [16][64][64][64] bf16 @ 0        (8,388,608)  [n][h][w][c], c-chunks
//                                                    XOR-swizzled by w&7
//   Wb [9][128][64] bf16    @ 8388608   (147,456)    swizzled by v&7
//   s  [65536] f32          @ 8536064   (262,144)    per-pixel channel sq-sum
// ---------------------------------------------------------------------------

// Fused prepass: blocks 0..1023 transpose x (fp32->bf16, swizzled) + sq-sum;
// blocks 1024..1055 normalize/reorder weights.
__global__ __launch_bounds__(256) void prep_all(
    const float* __restrict__ x, const float* __restrict__ w,
    const float* __restrict__ q, unsigned short* __restrict__ xT,
    unsigned short* __restrict__ Wb, float* __restrict__ s) {
  __shared__ float tile[64][65];
  int b = blockIdx.x;
  int tid = threadIdx.x;

  if (b >= 1024) {   // ---- weight path (32 blocks) ----
    int v = (b - 1024) * 4 + (tid >> 6);
    int c = tid & 63;
    float qn = q[0] * 0.01f;
    float scale = qn * qn;
    const float* wp = w + (v * 64 + c) * 9;
    float vals[9];
    float ss = 0.f;
#pragma unroll
    for (int j = 0; j < 9; ++j) { vals[j] = wp[j]; ss += vals[j] * vals[j]; }
#pragma unroll
    for (int off = 32; off > 0; off >>= 1) ss += __shfl_xor(ss, off);
    float inv = 1.0f / (sqrtf(ss + EPS) + scale);
    int pos = (((c >> 3) ^ (v & 7)) << 3) | (c & 7);
#pragma unroll
    for (int j = 0; j < 9; ++j) Wb[(j * 128 + v) * 64 + pos] = f2bf(vals[j] * inv);
    return;
  }

  // ---- x-transpose path (1024 blocks: n*64 + h) ----
  int n = b >> 6, h = b & 63;
  int c = tid >> 2, qq = tid & 3;
  const float* xp = x + ((size_t)(n * 64 + c)) * 4096 + h * 64;
#pragma unroll
  for (int k = 0; k < 4; ++k) {
    int w0 = qq * 16 + k * 4;
    float4 v4 = *(const float4*)(xp + w0);
    tile[c][w0 + 0] = v4.x; tile[c][w0 + 1] = v4.y;
    tile[c][w0 + 2] = v4.z; tile[c][w0 + 3] = v4.w;
  }
  __syncthreads();
  int ww = tid >> 2;
  float ss = 0.f;
  unsigned short* orow = xT + ((size_t)(n * 4096 + h * 64 + ww)) * 64;
#pragma unroll
  for (int t = 0; t < 2; ++t) {
    int slot = qq * 2 + t;
    int lc = slot ^ (ww & 7);          // logical chunk stored in this slot
    us8 st;
#pragma unroll
    for (int e = 0; e < 8; ++e) {
      float f = tile[lc * 8 + e][ww];
      ss += f * f;
      st[e] = f2bf(f);
    }
    *(us8*)(orow + slot * 8) = st;
  }
  ss += __shfl_xor(ss, 1);
  ss += __shfl_xor(ss, 2);
  if (qq == 0) s[n * 4096 + h * 64 + ww] = ss;
}

// Conv: 512 blocks x 256 thr (4 waves), 2 blocks/CU. Tile = 2 h-rows x 64 w
// x 128 v. x staged via global_load_lds (no reg roundtrip); xiv computed from
// global s while DMA is in flight; async-dbuf weights; 1 barrier per l.
__global__ __launch_bounds__(256, 2) void conv_mfma(
    const unsigned short* __restrict__ xT, const unsigned short* __restrict__ Wb,
    const float* __restrict__ s, const float* __restrict__ p,
    const float* __restrict__ q, float* __restrict__ out) {
  __shared__ unsigned short xs[4 * 66 * 64];  // [row][w+1][c] 33792 B, padded w
  __shared__ unsigned short wl[2 * 128 * 64]; // dbuf weight tiles, 32768 B
  __shared__ float xiv[2 * 64];               // 1/(sqrt(box3x3)+scale)

  int b = blockIdx.x;              // 512 = 16 n x 32 row-pairs
  int n = b >> 5, hg = b & 31;
  int h0 = hg * 2;
  int tid = threadIdx.x;
  int lane = tid & 63, wid = tid >> 6;
  int wv = wid & 1, wp = wid >> 1;     // v-half, output row
  int lp = lane & 15, lg = lane >> 4;

  auto stage_w = [&](int bufi, int l) {
    const unsigned short* src = Wb + l * 8192 + wid * 2048;
    unsigned short* dst = wl + bufi * 8192 + wid * 2048;
#pragma unroll
    for (int i = 0; i < 4; ++i)
      gl_lds16(src + i * 512 + lane * 8, dst + i * 512);
  };
  stage_w(0, 0);

  // ---- stage x rows h0-1..h0+2 via DMA: wave wid stages tile row wid ----
  {
    int hh = h0 - 1 + wid;
    unsigned short* dst = xs + wid * 4224 + 64;   // skip left pad column
    if ((unsigned)hh < 64u) {
      const unsigned short* src = xT + ((size_t)(n * 4096 + hh * 64)) * 64;
#pragma unroll
      for (int i = 0; i < 8; ++i)
        gl_lds16(src + i * 512 + lane * 8, dst + i * 512);
    } else {
      us8 z = {};
#pragma unroll
      for (int i = 0; i < 8; ++i)
        *(us8*)(dst + i * 512 + lane * 8) = z;
    }
  }
  // zero-pad columns w=-1 and w=64 for the 4 staged rows
  if (tid < 64) {
    int row = tid >> 4, side = (tid >> 3) & 1, j = tid & 7;
    us8 z = {};
    *(us8*)(xs + row * 4224 + (side ? 65 : 0) * 64 + j * 8) = z;
  }
  // ---- xiv from global s (overlaps the in-flight DMAs) ----
  if (tid < 128) {
    int r = tid >> 6, ww = tid & 63;
    int h = h0 + r;
    float qn = q[0] * 0.01f;
    float scale = qn * qn;
    const float* sp = s + n * 4096;
    float a = 0.f;
#pragma unroll
    for (int dh = -1; dh <= 1; ++dh) {
      int hh = h + dh;
      if ((unsigned)hh < 64u) {
#pragma unroll
        for (int dw = -1; dw <= 1; ++dw) {
          int w2 = ww + dw;
          if ((unsigned)w2 < 64u) a += sp[hh * 64 + w2];
        }
      }
    }
    xiv[r * 64 + ww] = 1.0f / (sqrtf(a + EPS) + scale);
  }

  f32x4 acc[4][4];   // [pg][vg]
#pragma unroll
  for (int i = 0; i < 4; ++i)
#pragma unroll
    for (int j = 0; j < 4; ++j) acc[i][j] = (f32x4){0.f, 0.f, 0.f, 0.f};

  __syncthreads();   // xs, xiv, wl(l=0) ready (vmcnt drained)

  int buf = 0;
#pragma unroll
  for (int l = 0; l < 9; ++l) {
    if (l < 8) stage_w(buf ^ 1, l + 1);   // async prefetch next l
    const int a = l / 3, bs = l % 3;
    const unsigned short* xrow = xs + (wp + a) * 4224;
    const unsigned short* wbase = wl + buf * 8192 + wv * 4096;
#pragma unroll
    for (int half = 0; half < 2; ++half) {
      const int cbase = half * 4;
      short8v av[4], bv[4];
#pragma unroll
      for (int vg = 0; vg < 4; ++vg)
        av[vg] = *(const short8v*)(wbase + (vg * 16 + lp) * 64 +
                                   ((cbase + lg) ^ (lp & 7)) * 8);
#pragma unroll
      for (int pg = 0; pg < 4; ++pg) {
        int wx = pg * 16 + lp + bs - 1;          // -1..64; pad cols are zero
        bv[pg] = *(const short8v*)(xrow + (wx + 1) * 64 +
                                   ((cbase + lg) ^ (wx & 7)) * 8);
      }
#pragma unroll
      for (int pg = 0; pg < 4; ++pg)
#pragma unroll
        for (int vg = 0; vg < 4; ++vg)
          acc[pg][vg] = __builtin_amdgcn_mfma_f32_16x16x32_bf16(
              bv[pg], av[vg], acc[pg][vg], 0, 0, 0);
    }
    if (l < 8) {
      __syncthreads();   // drains gl_lds (vmcnt) + everyone done reading buf
      buf ^= 1;
    }
  }

  // ---- epilogue: D[pixel][v]; lane: w4 = pg*16+lg*4, v = wv*64+vg*16+lp ----
  int h = h0 + wp;
#pragma unroll
  for (int vg = 0; vg < 4; ++vg) {
    int v = wv * 64 + vg * 16 + lp;
    float t0 = p[v] * 0.1f;
    float e = t0 * t0;
    float* ob = out + ((size_t)(n * 128 + v)) * 4096 + h * 64;
#pragma unroll
    for (int pg = 0; pg < 4; ++pg) {
      int w4 = pg * 16 + lg * 4;
      float4 xv = *(const float4*)&xiv[wp * 64 + w4];
      float yv[4] = {acc[pg][vg][0] * xv.x, acc[pg][vg][1] * xv.y,
                     acc[pg][vg][2] * xv.z, acc[pg][vg][3] * xv.w};
      f32x4 o;
#pragma unroll
      for (int r = 0; r < 4; ++r) {
        float y = yv[r];
        float t = fabsf(y) + EPS;
        float rv = exp2f(e * log2f(t));
        o[r] = (y == 0.0f) ? 0.0f : copysignf(rv, y);
      }
      *(f32x4*)(ob + w4) = o;
    }
  }
}

extern "C" void kernel_launch(void* const* d_in, const int* in_sizes, int n_in,
                              void* d_out, int out_size, void* d_ws, size_t ws_size,
                              hipStream_t stream) {
  const float* x = (const float*)d_in[0];   // [16,64,64,64]
  const float* w = (const float*)d_in[1];   // [128,64,9]
  const float* p = (const float*)d_in[2];   // [128]
  const float* q = (const float*)d_in[3];   // [1]
  float* out = (float*)d_out;               // [16,128,64,64]

  char* wsb = (char*)d_ws;
  unsigned short* xT = (unsigned short*)(wsb);
  unsigned short* Wb = (unsigned short*)(wsb + 8388608);
  float* s = (float*)(wsb + 8536064);

  prep_all<<<1056, 256, 0, stream>>>(x, w, q, xT, Wb, s);
  conv_mfma<<<512, 256, 0, stream>>>(xT, Wb, s, p, q, out);
}